// Round 1
// baseline (51.828 us; speedup 1.0000x reference)
//
#include <hip/hip_runtime.h>
#include <hip/hip_bf16.h>

#define NB   2
#define NH   16
#define NHKV 4
#define GQ   4
#define SQL  2048
#define SKV  2048
#define DH   64
#define QBLK 64
#define KVBLK 64
#define LDK  72   // padded leading dim (bf16 elems): 144B stride -> 2-way bank alias (free)

typedef __bf16 v8bf  __attribute__((ext_vector_type(8)));
typedef float  f32x4 __attribute__((ext_vector_type(4)));

__global__ __launch_bounds__(256, 2)
void gqa_seg_attn(const float* __restrict__ q,
                  const float* __restrict__ k,
                  const float* __restrict__ v,
                  const int* __restrict__ qseg,
                  const int* __restrict__ kvseg,
                  float* __restrict__ out)
{
    __shared__ __bf16 k_lds[KVBLK][LDK];   // [kv][d]
    __shared__ __bf16 vT_lds[DH][LDK];     // [d][kv]  (transposed V)
    __shared__ __bf16 p_lds[4][16][LDK];   // per-wave P re-layout buffer
    __shared__ int    kvseg_lds[KVBLK];

    const int tid  = threadIdx.x;
    const int lane = tid & 63;
    const int w    = tid >> 6;
    const int qt   = blockIdx.x;   // SQ/QBLK
    const int h    = blockIdx.y;
    const int b    = blockIdx.z;
    const int kvh  = h / GQ;
    const int q0   = qt * QBLK;

    const float* qptr  = q + (((size_t)b * NH   + h  ) * SQL) * DH;
    const float* kptr  = k + (((size_t)b * NHKV + kvh) * SKV) * DH;
    const float* vptr  = v + (((size_t)b * NHKV + kvh) * SKV) * DH;
    const int*   qsegb = qseg  + (size_t)b * SQL;
    const int*   kvsegb= kvseg + (size_t)b * SKV;

    const int l15 = lane & 15;
    const int lg  = lane >> 4;       // 16-lane group id (0..3)
    const int d_a = lg * 8;          // k-offset base within a 32-wide chunk

    // ---- Q fragments: lane reads rows (w*16 + l15), 8 contiguous d, scaled by 1/8 into bf16
    v8bf qfrag[2];
    {
        const int qrow = q0 + w * 16 + l15;
        for (int c = 0; c < 2; ++c) {
            const float* src = qptr + (size_t)qrow * DH + c * 32 + d_a;
            float4 f0 = *(const float4*)(src);
            float4 f1 = *(const float4*)(src + 4);
            v8bf t;
            t[0] = (__bf16)(f0.x * 0.125f); t[1] = (__bf16)(f0.y * 0.125f);
            t[2] = (__bf16)(f0.z * 0.125f); t[3] = (__bf16)(f0.w * 0.125f);
            t[4] = (__bf16)(f1.x * 0.125f); t[5] = (__bf16)(f1.y * 0.125f);
            t[6] = (__bf16)(f1.z * 0.125f); t[7] = (__bf16)(f1.w * 0.125f);
            qfrag[c] = t;
        }
    }

    // q segment ids for this lane's 4 C-fragment rows
    const int qrow_c0 = q0 + w * 16 + (lg << 2);
    int qsegr[4];
    for (int r = 0; r < 4; ++r) qsegr[r] = qsegb[qrow_c0 + r];

    // ---- valid KV range for this Q tile (segments sorted on both sides)
    const int smin = qsegb[q0];
    const int smax = qsegb[q0 + QBLK - 1];
    int lo, hi;
    {
        int a = 0, e = SKV;
        while (a < e) { int m = (a + e) >> 1; if (kvsegb[m] <  smin) a = m + 1; else e = m; }
        lo = a;
        a = lo; e = SKV;
        while (a < e) { int m = (a + e) >> 1; if (kvsegb[m] <= smax) a = m + 1; else e = m; }
        hi = a;
    }

    float m_run[4], l_run[4];
    f32x4 o_acc[4];
    for (int r = 0; r < 4; ++r) { m_run[r] = -__builtin_inff(); l_run[r] = 0.f; }
    for (int t = 0; t < 4; ++t) o_acc[t] = (f32x4){0.f, 0.f, 0.f, 0.f};

    int t0 = lo >> 6;
    int t1 = (hi + KVBLK - 1) >> 6;
    if (hi <= lo) t1 = t0;

    for (int kt = t0; kt < t1; ++kt) {
        const int kv0 = kt * KVBLK;
        __syncthreads();   // previous iteration's reads done before restage

        // ---- stage K tile (row-major bf16): thread -> row tid/4, 16 cols
        {
            const int row = tid >> 2, c0 = (tid & 3) * 16;
            const float* src = kptr + (size_t)(kv0 + row) * DH + c0;
            __bf16* dst = &k_lds[row][c0];
            for (int i = 0; i < 16; i += 4) {
                float4 f = *(const float4*)(src + i);
                dst[i+0] = (__bf16)f.x; dst[i+1] = (__bf16)f.y;
                dst[i+2] = (__bf16)f.z; dst[i+3] = (__bf16)f.w;
            }
        }
        // ---- stage V transposed: thread -> kv col (tid&63), 16 d rows
        {
            const int kvc = tid & 63, d0 = (tid >> 6) * 16;
            const float* src = vptr + (size_t)(kv0 + kvc) * DH + d0;
            for (int i = 0; i < 16; i += 4) {
                float4 f = *(const float4*)(src + i);
                vT_lds[d0+i+0][kvc] = (__bf16)f.x;
                vT_lds[d0+i+1][kvc] = (__bf16)f.y;
                vT_lds[d0+i+2][kvc] = (__bf16)f.z;
                vT_lds[d0+i+3][kvc] = (__bf16)f.w;
            }
        }
        if (tid < KVBLK) kvseg_lds[tid] = kvsegb[kv0 + tid];
        __syncthreads();

        // ---- QK^T: S[16 q][64 kv] per wave, 4 kv-subtiles x 2 d-chunks
        f32x4 s[4];
        for (int n = 0; n < 4; ++n) s[n] = (f32x4){0.f, 0.f, 0.f, 0.f};
        for (int n = 0; n < 4; ++n)
            for (int c = 0; c < 2; ++c) {
                v8bf kb = *(const v8bf*)&k_lds[n * 16 + l15][c * 32 + d_a];
                s[n] = __builtin_amdgcn_mfma_f32_16x16x32_bf16(qfrag[c], kb, s[n], 0, 0, 0);
            }

        // ---- mask + tile row-max
        int kvs[4];
        for (int n = 0; n < 4; ++n) kvs[n] = kvseg_lds[n * 16 + l15];
        float mt[4];
        for (int r = 0; r < 4; ++r) mt[r] = -__builtin_inff();
        for (int n = 0; n < 4; ++n)
            for (int r = 0; r < 4; ++r) {
                float sv = (kvs[n] == qsegr[r]) ? s[n][r] : -__builtin_inff();
                s[n][r] = sv;
                mt[r] = fmaxf(mt[r], sv);
            }
        for (int r = 0; r < 4; ++r) {
            float x = mt[r];
            for (int d = 1; d < 16; d <<= 1) x = fmaxf(x, __shfl_xor(x, d));
            mt[r] = x;
        }

        // ---- online softmax update
        float alpha[4], psum[4];
        for (int r = 0; r < 4; ++r) {
            float mn = fmaxf(m_run[r], mt[r]);
            if (mn == -__builtin_inff()) { alpha[r] = 1.f; }
            else { alpha[r] = __expf(m_run[r] - mn); m_run[r] = mn; }
            psum[r] = 0.f;
        }
        for (int n = 0; n < 4; ++n)
            for (int r = 0; r < 4; ++r) {
                float pv = 0.f;
                if (s[n][r] != -__builtin_inff()) pv = __expf(s[n][r] - m_run[r]);
                psum[r] += pv;
                p_lds[w][(lg << 2) + r][n * 16 + l15] = (__bf16)pv;
            }
        for (int r = 0; r < 4; ++r) {
            float x = psum[r];
            for (int d = 1; d < 16; d <<= 1) x += __shfl_xor(x, d);
            l_run[r] = l_run[r] * alpha[r] + x;
        }
        for (int t = 0; t < 4; ++t)
            for (int r = 0; r < 4; ++r) o_acc[t][r] *= alpha[r];

        // ---- PV: O[16 q][64 d] += P[16 q][64 kv] * V[64 kv][64 d]
        v8bf pa[2];
        for (int c = 0; c < 2; ++c)
            pa[c] = *(const v8bf*)&p_lds[w][l15][c * 32 + d_a];
        for (int t = 0; t < 4; ++t)
            for (int c = 0; c < 2; ++c) {
                v8bf vb = *(const v8bf*)&vT_lds[t * 16 + l15][c * 32 + d_a];
                o_acc[t] = __builtin_amdgcn_mfma_f32_16x16x32_bf16(pa[c], vb, o_acc[t], 0, 0, 0);
            }
    }

    // ---- epilogue: normalize, fully-masked rows -> 0
    float* outp = out + (((size_t)b * NH + h) * SQL) * DH;
    for (int r = 0; r < 4; ++r) {
        float inv = (l_run[r] > 0.f) ? (1.f / l_run[r]) : 0.f;
        for (int t = 0; t < 4; ++t)
            outp[(size_t)(qrow_c0 + r) * DH + t * 16 + l15] = o_acc[t][r] * inv;
    }
}

extern "C" void kernel_launch(void* const* d_in, const int* in_sizes, int n_in,
                              void* d_out, int out_size, void* d_ws, size_t ws_size,
                              hipStream_t stream) {
    const float* q     = (const float*)d_in[0];
    const float* k     = (const float*)d_in[1];
    const float* v     = (const float*)d_in[2];
    const int*   qseg  = (const int*)d_in[3];
    const int*   kvseg = (const int*)d_in[4];
    float* out = (float*)d_out;

    dim3 grid(SQL / QBLK, NH, NB);
    dim3 block(256);
    gqa_seg_attn<<<grid, block, 0, stream>>>(q, k, v, qseg, kvseg, out);
}